// Round 2
// baseline (682.169 us; speedup 1.0000x reference)
//
#include <hip/hip_runtime.h>

// VertexSplitter: B=256, V=512.
// out = (M > 0) where M = (Pid > 0) with 8 per-batch conditional edits.
// Output is (out, out) concatenated -> 2 * B*V*V floats.
//
// R2: streaming rewrite of fill_kernel (R1 + compile fix).
//  - nontemporal loads/stores (nt flag): none of the 3 streams (Pid read,
//    out copy0, out copy1) has reuse; L2 write-allocate on 2x256MiB store
//    streams was the theory for the ~2.4 TB/s effective BW.
//  - __builtin_nontemporal_* requires a clang native vector type, not
//    HIP_vector_type<float,4> -> use ext_vector_type(4).
//  - UNROLL=4 float4/thread: 4 outstanding loads before the store burst
//    (MLP to cover HBM latency). 16,777,216 float4s = 16384 blocks * 256
//    threads * 4 -> exact divide, no tail/bounds check.

#define BATCH 256
#define VDIM 512
#define UNROLL 4

typedef float floatx4 __attribute__((ext_vector_type(4)));

__global__ void __launch_bounds__(256) fill_kernel(const floatx4* __restrict__ pid,
                                                   floatx4* __restrict__ out,
                                                   long long n4) {
    // Each block covers a contiguous chunk of 256*UNROLL float4s;
    // thread t handles t, t+256, t+512, t+768 -> every instruction is
    // a fully-coalesced 1 KiB wave access.
    long long base = (long long)blockIdx.x * (256 * UNROLL) + threadIdx.x;

    floatx4 p[UNROLL];
#pragma unroll
    for (int u = 0; u < UNROLL; ++u) {
        p[u] = __builtin_nontemporal_load(&pid[base + u * 256]);
    }

#pragma unroll
    for (int u = 0; u < UNROLL; ++u) {
        floatx4 o;
        o.x = p[u].x > 0.f ? 1.f : 0.f;
        o.y = p[u].y > 0.f ? 1.f : 0.f;
        o.z = p[u].z > 0.f ? 1.f : 0.f;
        o.w = p[u].w > 0.f ? 1.f : 0.f;
        __builtin_nontemporal_store(o, &out[base + u * 256]);        // copy 0
        __builtin_nontemporal_store(o, &out[base + u * 256 + n4]);   // copy 1
    }
}

__global__ void __launch_bounds__(256) edit_kernel(const float* __restrict__ pid,
                                                   const int* __restrict__ inter,
                                                   float* __restrict__ out,
                                                   long long n) {
    int b = blockIdx.x * blockDim.x + threadIdx.x;
    if (b >= BATCH) return;

    int e10 = inter[b * 4 + 0];
    int e11 = inter[b * 4 + 1];
    int e20 = inter[b * 4 + 2];
    int e21 = inter[b * 4 + 3];

    bool distinct = (e10 != e11) && (e10 != e20) && (e10 != e21) &&
                    (e11 != e20) && (e11 != e21) && (e20 != e21);

    const float* P = pid + (long long)b * VDIM * VDIM;
    // blocked / old_pid read from ORIGINAL M = (Pid > 0), before any edits
    bool blocked = (P[(long long)e10 * VDIM + e20] > 0.f) ||
                   (P[(long long)e11 * VDIM + e21] > 0.f);
    bool valid = distinct && !blocked;
    if (!valid) return;

    float old_pid = (P[(long long)e10 * VDIM + e11] > 0.f) ? 1.f : 0.f;

    float* O0 = out + (long long)b * VDIM * VDIM;
    float* O1 = O0 + n;

    // All 8 ordered positions are distinct when valid (4 distinct vertices),
    // so the sequential csets reduce to independent stores.
    long long i_1011 = (long long)e10 * VDIM + e11;
    long long i_1110 = (long long)e11 * VDIM + e10;
    long long i_2021 = (long long)e20 * VDIM + e21;
    long long i_2120 = (long long)e21 * VDIM + e20;
    long long i_1020 = (long long)e10 * VDIM + e20;
    long long i_2010 = (long long)e20 * VDIM + e10;
    long long i_1121 = (long long)e11 * VDIM + e21;
    long long i_2111 = (long long)e21 * VDIM + e11;

    O0[i_1011] = 0.f;      O1[i_1011] = 0.f;
    O0[i_1110] = 0.f;      O1[i_1110] = 0.f;
    O0[i_2021] = 0.f;      O1[i_2021] = 0.f;
    O0[i_2120] = 0.f;      O1[i_2120] = 0.f;
    O0[i_1020] = old_pid;  O1[i_1020] = old_pid;
    O0[i_2010] = old_pid;  O1[i_2010] = old_pid;
    O0[i_1121] = 1.f;      O1[i_1121] = 1.f;
    O0[i_2111] = 1.f;      O1[i_2111] = 1.f;
}

extern "C" void kernel_launch(void* const* d_in, const int* in_sizes, int n_in,
                              void* d_out, int out_size, void* d_ws, size_t ws_size,
                              hipStream_t stream) {
    const float* pid  = (const float*)d_in[0];   // (B, V, V) float32
    const int* inter  = (const int*)d_in[1];     // (B, 2, 2) int32
    float* out        = (float*)d_out;           // 2 * B*V*V float32

    long long n  = (long long)BATCH * VDIM * VDIM;  // 67,108,864
    long long n4 = n / 4;                           // 16,777,216 float4s

    dim3 block(256);
    dim3 grid((unsigned)(n4 / (256 * UNROLL)));     // 16,384 blocks, exact
    fill_kernel<<<grid, block, 0, stream>>>((const floatx4*)pid, (floatx4*)out, n4);
    edit_kernel<<<1, 256, 0, stream>>>(pid, inter, out, n);
}